// Round 6
// baseline (1400.910 us; speedup 1.0000x reference)
//
#include <hip/hip_runtime.h>

#define G_    128
#define NV_   32
#define EPG_  64
#define LEPG_ 256
#define NG_   (G_*NV_)      // 4096
#define NLG_  (G_*EPG_)     // 8192
#define ELG_  (G_*LEPG_)    // 32768
#define K_    64
#define H_    32
#define HF_   128
#define L_    4
#define NC_   12
#define FIN_  16
#define FE_   16
#define NB_   4
#define TILE_ (K_*H_)       // 2048

// ---------------------------------------------------------------------------
// Kernel A: init + pre(enc,glob) + p12 + q34 + csr — independent roles by bid
__global__ __launch_bounds__(256) void kA(
    const float* __restrict__ xg, const float* __restrict__ Wenc,
    const float* __restrict__ benc,
    const float* __restrict__ ealg, const float* __restrict__ gaw,
    const float* __restrict__ gab,
    const float* __restrict__ xlg, const float* __restrict__ gdw,
    const float* __restrict__ gdb,
    const float* __restrict__ eag, const float* __restrict__ Wm,
    const float* __restrict__ bm,
    const int* __restrict__ ls, const int* __restrict__ ldst,
    float* __restrict__ h, float* __restrict__ eglob, float* __restrict__ dglob,
    float* __restrict__ p1, float* __restrict__ p2, float* __restrict__ q34,
    int* __restrict__ offsg, int* __restrict__ csrp, float* __restrict__ bna)
{
    __shared__ int cnt[64], offs[65], cur[64];
    int bid = blockIdx.x, t = threadIdx.x;
    if (bid == 0) {
        bna[t] = 0.f;
        return;
    }
    if (bid < 1 + 1152) {
        int lb = bid - 1;
        if (lb < 512) {
            int gid = lb*256 + t; int nn = gid>>5, ch = gid&31;
            float s = benc[ch];
#pragma unroll
            for (int f = 0; f < FIN_; ++f) s += xg[nn*FIN_+f]*Wenc[f*H_+ch];
            h[gid] = s;
        } else {
            int gid = (lb-512)*256 + t;
            if (gid < ELG_*4) {
                int e = gid>>2, k = gid&3;
                float s = gab[k];
#pragma unroll
                for (int j = 0; j < 4; ++j) s += ealg[e*4+j]*gaw[j*4+k];
                eglob[gid] = s;
            } else {
                int gid2 = gid - ELG_*4;
                int nn = gid2>>2, k = gid2&3;
                float s = gdb[k];
#pragma unroll
                for (int j = 0; j < 4; ++j) s += xlg[nn*4+j]*gdw[j*4+k];
                dglob[gid2] = s;
            }
        }
        return;
    }
    if (bid < 1 + 1152 + 2048) {
        int lb = bid - 1153;
        int n = lb*2 + (t>>7), o = t&127;
        // compute h row inline (avoids cross-block dependency within this launch)
        float hv[32];
#pragma unroll
        for (int k = 0; k < 32; ++k) {
            float s = benc[k];
#pragma unroll
            for (int f = 0; f < FIN_; ++f) s += xg[n*FIN_+f]*Wenc[f*H_+k];
            hv[k] = s;
        }
        float a = 0.f, b = 0.f;
#pragma unroll
        for (int k = 0; k < 32; ++k) {
            a += hv[k] * Wm[k*HF_ + o];
            b += hv[k] * Wm[(32+k)*HF_ + o];
        }
        p1[n*HF_ + o] = a; p2[n*HF_ + o] = b;
        return;
    }
    if (bid < 1 + 1152 + 2048 + 4096) {
        int lb = bid - 3201;
        int e = lb*2 + (t>>7), o = t&127;
        float s = bm[o];
#pragma unroll
        for (int k = 0; k < 16; ++k) s += eag[e*16+k] * Wm[(64+k)*HF_ + o];
#pragma unroll
        for (int k = 0; k < 4; ++k)  s += xlg[e*4+k]  * Wm[(80+k)*HF_ + o];
        q34[e*HF_ + o] = s;
        return;
    }
    {   // csr role
        int g = bid - 7297;
        if (t < 64) cnt[t] = 0;
        __syncthreads();
        int d = ldst[g*256 + t] & 63;
        int sl = ls[g*256 + t] & 63;
        atomicAdd(&cnt[d], 1);
        __syncthreads();
        if (t == 0) {
            int a = 0;
            for (int i = 0; i < 64; ++i) { offs[i] = a; a += cnt[i]; }
            offs[64] = a;
        }
        __syncthreads();
        if (t < 64) { cur[t] = offs[t]; offsg[g*65 + t] = offs[t]; }
        if (t == 0) offsg[g*65 + 64] = offs[64];
        __syncthreads();
        int p = atomicAdd(&cur[d], 1);
        csrp[g*256 + p] = (t << 6) | sl;
    }
}

// ---------------------------------------------------------------------------
// Kernel B: msg2 (hm gather-add) + dlef (all layers) — roles by bid
__global__ __launch_bounds__(256) void kB(
    const float* __restrict__ p1, const float* __restrict__ p2,
    const float* __restrict__ q34, const int* __restrict__ sidx,
    const int* __restrict__ didx, float* __restrict__ hm,
    const float* __restrict__ dgl, const float* __restrict__ egl,
    const float* __restrict__ ldw, const float* __restrict__ ldb,
    const float* __restrict__ law, const float* __restrict__ lab,
    const float* __restrict__ enw, const float* __restrict__ enb,
    float* __restrict__ dlb, float* __restrict__ efb)
{
    __shared__ float el[8][32];
    int bid = blockIdx.x, t = threadIdx.x;
    if (bid < 1024) {
        int idx = bid*256 + t;     // NLG*32 float4s
        int e = idx >> 5, o4 = idx & 31;
        int s = sidx[e], d = didx[e];
        float4 a = ((const float4*)p1)[s*32 + o4];
        float4 b = ((const float4*)p2)[d*32 + o4];
        float4 q = ((const float4*)q34)[e*32 + o4];
        ((float4*)hm)[idx] = make_float4(a.x+b.x+q.x, a.y+b.y+q.y, a.z+b.z+q.z, a.w+b.w+q.w);
        return;
    }
    int lb = bid - 1024;
    if (lb < 4096) {
        int gid = lb*256 + t;
        int l = gid >> 18, rem = gid & ((1<<18)-1);
        int n = rem >> 5, ch = rem & 31;
        float s = ldb[l*32 + ch];
#pragma unroll
        for (int j = 0; j < 4; ++j) s += dgl[n*4+j] * ldw[l*128 + j*32 + ch];
        dlb[gid] = s;
    } else {
        int p = (lb - 4096)*8 + (t >> 5);
        int ch = t & 31;
        int l = p >> 15, e = p & 32767;
        float s = lab[l*32 + ch];
#pragma unroll
        for (int j = 0; j < 4; ++j) s += egl[e*4+j] * law[l*128 + j*32 + ch];
        el[t>>5][ch] = s;
        __syncthreads();
        float o = enb[l*32 + ch];
        for (int k = 0; k < 32; ++k) o += el[t>>5][k] * enw[l*1024 + k*32 + ch];
        efb[(size_t)l*ELG_*32 + e*32 + ch] = o;
    }
}

// ---------------------------------------------------------------------------
// Kernel C: rv (+layer-0 cs/ds stats) + out0 — roles by bid
__global__ __launch_bounds__(256) void kC(
    const float* __restrict__ hm, const float* __restrict__ Wi,
    const float* __restrict__ bi, float* __restrict__ rv,
    float* __restrict__ cs, float* __restrict__ ds,
    const float* __restrict__ l1w, const float* __restrict__ l1b,
    const float* __restrict__ l2w, const float* __restrict__ l2b,
    const float* __restrict__ lnw, const float* __restrict__ lnb,
    float* __restrict__ out_acc)
{
    __shared__ float mh[128], o1[128];
    int bid = blockIdx.x, t = threadIdx.x;
    if (bid < 1024) {
        int n = bid*8 + (t>>5), ch = t&31;
        float s = Wi[ch];
        for (int f = 0; f < HF_; ++f) s += hm[n*HF_ + f] * Wi[(1+f)*H_ + ch];
        rv[n*32 + ch] = s;
        cs[n*32 + ch] = 64.f*bi[ch] + s;
        ds[n*32 + ch] = bi[ch] + s;
        return;
    }
    int g = bid - 1024;
    if (t < 128) {
        float s = 0.f;
        for (int k = 0; k < 64; ++k) s += hm[(g*64+k)*HF_ + t];
        mh[t] = s * (1.f/64.f);
    }
    __syncthreads();
    float o = 0.f;
    if (t < 128) {
        o = l1b[t] + l2b[t] + (l1w[t]*(1.f/64.f) + l2w[t]);
        for (int k = 0; k < 128; ++k)
            o += mh[k] * (l1w[(1+k)*HF_ + t]*(1.f/64.f) + l2w[(1+k)*HF_ + t]);
        o1[t] = o;
    }
    __syncthreads();
    if (t < 128) {
        float r = lnb[t];
        for (int k = 0; k < 128; ++k) r += o1[k] * lnw[k*HF_ + t];
        out_acc[g*HF_ + t] = o + (r > 0.f ? r : 0.f);
    }
}

// gtdl for one layer (BN fold inline from bna) + zero next stats accumulators
__global__ __launch_bounds__(256) void k_gtdl(
    const float* __restrict__ cs, const float* __restrict__ ds,
    const float* __restrict__ bnaP, const float* __restrict__ bng,
    const float* __restrict__ bnb, int lay,
    const float* __restrict__ u1w, const float* __restrict__ u2w,
    const float* __restrict__ u3w, const float* __restrict__ u1b,
    const float* __restrict__ u2b, const float* __restrict__ u3b,
    const float* __restrict__ dl_l, float* __restrict__ gtb,
    float* __restrict__ csZ, float* __restrict__ ssZ) {
    int idx = blockIdx.x*256 + threadIdx.x;
    int n = idx >> 5, ch = idx & 31;
    int chi = ch & 3, twb = ch & ~3;
    float gt = u1b[ch] + u2b[ch] + u3b[ch];
#pragma unroll
    for (int j = 0; j < 4; ++j) {
        int bj = twb + j;
        float s_ = 1.f, sh_ = 0.f;
        if (lay > 0) {
            float m = bnaP[bj] * (1.f/524288.f);
            float v = bnaP[32+bj] * (1.f/524288.f) - m*m;
            s_ = bng[bj] * rsqrtf(v + 1e-5f);
            sh_ = bnb[bj] - m*s_;
        }
        float csF = s_*cs[n*32 + bj] + 64.f*sh_;
        float dgF = s_*ds[n*32 + bj] + sh_;
        gt += csF*(1.f/64.f)*u2w[bj*4 + chi] + dgF*u3w[bj*4 + chi]
            + sh_*u1w[bj*4 + chi];
    }
    gtb[idx] = gt * dl_l[idx];
    csZ[idx] = 0.f;
    ssZ[idx] = 0.f;
}

// ---------------------------------------------------------------------------
// main layer kernel: 256 threads, block = (graph, 2-color chunk).
// um in LDS (16KB); own u in regs; per-node staged edge phase (low VGPR).
#define UM_NODE(I, UOI)                                                     \
  {                                                                         \
    float4 dl = *(const float4*)(dl_l + (((size_t)(n0g+I))<<5) + chb);      \
    float4 gt = *(const float4*)(gtb  + (((size_t)(n0g+I))<<5) + chb);      \
    float m0 = (UOI.x*w1f[0]+UOI.y*w1f[4]+UOI.z*w1f[8] +UOI.w*w1f[12])*dl.x + gt.x; \
    float m1 = (UOI.x*w1f[1]+UOI.y*w1f[5]+UOI.z*w1f[9] +UOI.w*w1f[13])*dl.y + gt.y; \
    float m2 = (UOI.x*w1f[2]+UOI.y*w1f[6]+UOI.z*w1f[10]+UOI.w*w1f[14])*dl.z + gt.z; \
    float m3 = (UOI.x*w1f[3]+UOI.y*w1f[7]+UOI.z*w1f[11]+UOI.w*w1f[15])*dl.w + gt.w; \
    *(float4*)&um[(nq*4+I)*64 + coff] = make_float4(m0,m1,m2,m3);           \
  }

#define EDGE_UN_NODE(I, UOI)                                                \
  {                                                                         \
    const int nI = nq*4 + I;                                                \
    float4 mo = *(float4*)&um[nI*64 + coff];                                \
    float4 ui;                                                              \
    ui.x = bli4[0] + mo.x*wi[0] + mo.y*wi[4] + mo.z*wi[8]  + mo.w*wi[12];   \
    ui.y = bli4[1] + mo.x*wi[1] + mo.y*wi[5] + mo.z*wi[9]  + mo.w*wi[13];   \
    ui.z = bli4[2] + mo.x*wi[2] + mo.y*wi[6] + mo.z*wi[10] + mo.w*wi[14];   \
    ui.w = bli4[3] + mo.x*wi[3] + mo.y*wi[7] + mo.z*wi[11] + mo.w*wi[15];   \
    float4 acc = make_float4(0.f,0.f,0.f,0.f);                              \
    const int je = offs[nI+1];                                              \
    for (int j = offs[nI]; j < je; ++j) {                                   \
        int pk = ep[j];                                                     \
        float4 ef4 = *(const float4*)(ef_l + (((size_t)((g<<8)+(pk>>6)))<<5) + chb); \
        float4 u4 = *(float4*)&um[(pk & 63)*64 + coff];                     \
        float r0 = ui.x + ef4.x + blj4[0] + u4.x*wj[0] + u4.y*wj[4] + u4.z*wj[8]  + u4.w*wj[12]; \
        float r1 = ui.y + ef4.y + blj4[1] + u4.x*wj[1] + u4.y*wj[5] + u4.z*wj[9]  + u4.w*wj[13]; \
        float r2 = ui.z + ef4.z + blj4[2] + u4.x*wj[2] + u4.y*wj[6] + u4.z*wj[10] + u4.w*wj[14]; \
        float r3 = ui.w + ef4.w + blj4[3] + u4.x*wj[3] + u4.y*wj[7] + u4.z*wj[11] + u4.w*wj[15]; \
        acc.x += u4.x + (r0>0.f?r0:0.f);                                    \
        acc.y += u4.y + (r1>0.f?r1:0.f);                                    \
        acc.z += u4.z + (r2>0.f?r2:0.f);                                    \
        acc.w += u4.w + (r3>0.f?r3:0.f);                                    \
    }                                                                       \
    float4 un4;                                                             \
    un4.x = acc.x*0.25f + sc4[0]*UOI.x + sh4[0];                            \
    un4.y = acc.y*0.25f + sc4[1]*UOI.y + sh4[1];                            \
    un4.z = acc.z*0.25f + sc4[2]*UOI.z + sh4[2];                            \
    un4.w = acc.w*0.25f + sc4[3]*UOI.w + sh4[3];                            \
    if (!last)                                                              \
        *(float4*)(u_out + (((size_t)(n0g+I))<<11) + (ck<<6) + coff) = un4; \
    if (col0 == nI)                                                         \
        *(float4*)&dsb[(((size_t)(n0g+I))<<5) + chb] = un4;                 \
    float cx=un4.x, cy=un4.y, cz=un4.z, cw=un4.w;                           \
    float qx=cx*cx, qy=cy*cy, qz=cz*cz, qw=cw*cw;                           \
    cx+=__shfl_xor(cx,8); cy+=__shfl_xor(cy,8); cz+=__shfl_xor(cz,8); cw+=__shfl_xor(cw,8); \
    qx+=__shfl_xor(qx,8); qy+=__shfl_xor(qy,8); qz+=__shfl_xor(qz,8); qw+=__shfl_xor(qw,8); \
    int nb32 = ((n0g+I) << 5) + chb;                                        \
    if (c == 0) {                                                           \
        atomicAdd(&csO[nb32+0], cx); atomicAdd(&csO[nb32+1], cy);           \
        atomicAdd(&csO[nb32+2], cz); atomicAdd(&csO[nb32+3], cw);           \
    } else {                                                                \
        atomicAdd(&ssO[nb32+0], qx); atomicAdd(&ssO[nb32+1], qy);           \
        atomicAdd(&ssO[nb32+2], qz); atomicAdd(&ssO[nb32+3], qw);           \
    }                                                                       \
  }

__global__ __launch_bounds__(256, 6) void k_layer(
    const float* __restrict__ u_in, float* __restrict__ u_out,
    const int* __restrict__ offsg, const int* __restrict__ csrp,
    const float* __restrict__ bnaP, const float* __restrict__ bng,
    const float* __restrict__ bnb, int lay, int last,
    const float* __restrict__ rvb, const float* __restrict__ bi,
    const float* __restrict__ u1w,
    const float* __restrict__ liw, const float* __restrict__ lib,
    const float* __restrict__ ljw, const float* __restrict__ ljb,
    const float* __restrict__ dl_l, const float* __restrict__ gtb,
    const float* __restrict__ ef_l,
    float* __restrict__ csO, float* __restrict__ ssO, float* __restrict__ dsb)
{
    __shared__ float um[64*64];     // 16 KB
    __shared__ int ep[256];
    __shared__ int offs[65];

    const int bid = blockIdx.x, t = threadIdx.x;
    const int g  = ((bid >> 8) << 3) | (bid & 7);   // XCD swizzle, 4096%8==0
    const int ck = (bid >> 3) & 31;                 // 2-color chunk
    const int tw = t & 7, c = (t >> 3) & 1, nq = t >> 4;   // nq in [0,16)
    const int chb = tw * 4;
    const int coff = c*32 + chb;                    // [0,64)
    const int n0g = g*64 + nq*4;
    const int col0 = ck*2 + c;                      // this thread's global color

    ep[t] = csrp[g*256 + t];
    if (t < 65) offs[t] = offsg[g*65 + t];

    // own u (registers)
    float4 uo0, uo1, uo2, uo3;
    if (lay == 0) {
        float4 b4 = *(const float4*)(bi + chb);
        uo0 = b4; uo1 = b4; uo2 = b4; uo3 = b4;
        int d = col0 - nq*4;
        if (d >= 0 && d < 4) {
            float4 r = *(const float4*)(rvb + (size_t)(n0g + d)*32 + chb);
            if      (d == 0) { uo0.x+=r.x; uo0.y+=r.y; uo0.z+=r.z; uo0.w+=r.w; }
            else if (d == 1) { uo1.x+=r.x; uo1.y+=r.y; uo1.z+=r.z; uo1.w+=r.w; }
            else if (d == 2) { uo2.x+=r.x; uo2.y+=r.y; uo2.z+=r.z; uo2.w+=r.w; }
            else             { uo3.x+=r.x; uo3.y+=r.y; uo3.z+=r.z; uo3.w+=r.w; }
        }
    } else {
        const float* ub = u_in + ((size_t)n0g << 11) + (ck << 6) + coff;
        uo0 = *(const float4*)(ub);
        uo1 = *(const float4*)(ub + 2048);
        uo2 = *(const float4*)(ub + 4096);
        uo3 = *(const float4*)(ub + 6144);
    }

    // BN fold
    float sc4[4], sh4[4];
    if (lay > 0) {
#pragma unroll
        for (int j2 = 0; j2 < 4; ++j2) {
            int bj = chb + j2;
            float m = bnaP[bj] * (1.f/524288.f);
            float v = bnaP[32+bj] * (1.f/524288.f) - m*m;
            float s_ = bng[bj] * rsqrtf(v + 1e-5f);
            sc4[j2] = s_; sh4[j2] = bnb[bj] - m*s_;
        }
    } else {
#pragma unroll
        for (int j2 = 0; j2 < 4; ++j2) { sc4[j2] = 1.f; sh4[j2] = 0.f; }
    }
    // weights (w1f dies at barrier; wi/wj live through edge phase)
    float wi[16], wj[16], bli4[4], blj4[4];
#pragma unroll
    for (int j2 = 0; j2 < 4; ++j2)
#pragma unroll
        for (int d = 0; d < 4; ++d) {
            wi[j2*4+d] = liw[(chb+j2)*4 + d];
            wj[j2*4+d] = ljw[(chb+j2)*4 + d];
        }
#pragma unroll
    for (int d = 0; d < 4; ++d) { bli4[d] = lib[chb+d]; blj4[d] = ljb[chb+d]; }

    {
        float w1f[16];
#pragma unroll
        for (int j2 = 0; j2 < 4; ++j2)
#pragma unroll
            for (int d = 0; d < 4; ++d)
                w1f[j2*4+d] = u1w[(chb+j2)*4 + d] * sc4[j2];
        UM_NODE(0, uo0)
        UM_NODE(1, uo1)
        UM_NODE(2, uo2)
        UM_NODE(3, uo3)
    }
    __syncthreads();

    EDGE_UN_NODE(0, uo0)
    EDGE_UN_NODE(1, uo1)
    EDGE_UN_NODE(2, uo2)
    EDGE_UN_NODE(3, uo3)
}

// per-graph reduce of cs/ss/ds + bn accumulation + graph extract (+final head)
__global__ __launch_bounds__(256) void k_midx(
    const float* __restrict__ cs, const float* __restrict__ ss,
    const float* __restrict__ ds,
    const float* __restrict__ l1w, const float* __restrict__ l1b,
    const float* __restrict__ l2w, const float* __restrict__ l2b,
    const float* __restrict__ lnw, const float* __restrict__ lnb,
    float* __restrict__ bna_i, float* __restrict__ out_acc, float scale,
    int do_final, const float* __restrict__ acw, const float* __restrict__ acb,
    const float* __restrict__ flw, const float* __restrict__ flb,
    float* __restrict__ outp)
{
    __shared__ float red[3*128];
    __shared__ float S[32], D[32], o1[128], ov[128], t1[128];
    int g = blockIdx.x, t = threadIdx.x;
    int ch = t & 31, ng = t >> 5;
    float pS = 0.f, pQ = 0.f, pD = 0.f;
#pragma unroll
    for (int k = 0; k < 8; ++k) {
        int n = g*64 + ng*8 + k;
        pS += cs[n*32 + ch];
        pQ += ss[n*32 + ch];
        pD += ds[n*32 + ch];
    }
    pS += __shfl_xor(pS, 32); pQ += __shfl_xor(pQ, 32); pD += __shfl_xor(pD, 32);
    int w = t >> 6;
    if ((t & 63) < 32) {
        red[w*32 + ch] = pS;
        red[128 + w*32 + ch] = pQ;
        red[256 + w*32 + ch] = pD;
    }
    __syncthreads();
    if (t < 32) {
        float S_ = 0.f, Q_ = 0.f, D_ = 0.f;
#pragma unroll
        for (int ww = 0; ww < 4; ++ww) {
            S_ += red[ww*32 + t]; Q_ += red[128 + ww*32 + t]; D_ += red[256 + ww*32 + t];
        }
        S[t] = S_; D[t] = D_;
        atomicAdd(&bna_i[t], S_);
        atomicAdd(&bna_i[32 + t], Q_);
    }
    __syncthreads();
    float o = 0.f;
    if (t < 128) {
        o = l1b[t] + l2b[t];
        for (int k = 0; k < 32; ++k)
            o += (S[k]*(1.f/4096.f))*l1w[k*HF_ + t] + (D[k]*(1.f/64.f))*l2w[k*HF_ + t];
        o1[t] = o;
    }
    __syncthreads();
    if (t < 128) {
        float r = lnb[t];
        for (int k = 0; k < 128; ++k) r += o1[k] * lnw[k*HF_ + t];
        float newv = out_acc[g*HF_ + t] + (o + (r > 0.f ? r : 0.f)) * scale;
        out_acc[g*HF_ + t] = newv;
        ov[t] = newv;
    }
    if (do_final) {
        __syncthreads();
        if (t < 128) {
            float r2 = acb[t];
            for (int k = 0; k < 128; ++k) r2 += ov[k] * acw[k*HF_ + t];
            t1[t] = ov[t] + (r2 > 0.f ? r2 : 0.f);
        }
        __syncthreads();
        if (t < NC_) {
            float s2 = flb[t];
            for (int k = 0; k < 128; ++k) s2 += t1[k] * flw[k*NC_ + t];
            outp[g*NC_ + t] = s2;
        }
    }
}

// ---------------------------------------------------------------------------
extern "C" void kernel_launch(void* const* d_in, const int* in_sizes, int n_in,
                              void* d_out, int out_size, void* d_ws, size_t ws_size,
                              hipStream_t stream) {
    const float* x_g      = (const float*)d_in[0];
    const float* eag      = (const float*)d_in[1];
    const float* x_lg     = (const float*)d_in[2];
    const float* ealg     = (const float*)d_in[3];
    const float* W_enc    = (const float*)d_in[4];
    const float* b_enc    = (const float*)d_in[5];
    const float* W_msg    = (const float*)d_in[6];
    const float* b_msg    = (const float*)d_in[7];
    const float* W_init   = (const float*)d_in[8];
    const float* b_init   = (const float*)d_in[9];
    const float* np_l1_w  = (const float*)d_in[10];
    const float* np_l1_b  = (const float*)d_in[11];
    const float* np_l2_w  = (const float*)d_in[12];
    const float* np_l2_b  = (const float*)d_in[13];
    const float* np_lin_w = (const float*)d_in[14];
    const float* np_lin_b = (const float*)d_in[15];
    const float* fe_l1_w  = (const float*)d_in[16];
    const float* fe_l1_b  = (const float*)d_in[17];
    const float* fe_l2_w  = (const float*)d_in[18];
    const float* fe_l2_b  = (const float*)d_in[19];
    const float* fe_lin_w = (const float*)d_in[20];
    const float* fe_lin_b = (const float*)d_in[21];
    const float* gd_w     = (const float*)d_in[22];
    const float* gd_b     = (const float*)d_in[23];
    const float* ga_w     = (const float*)d_in[24];
    const float* ga_b     = (const float*)d_in[25];
    const float* ld_w     = (const float*)d_in[26];
    const float* ld_b     = (const float*)d_in[27];
    const float* la_w     = (const float*)d_in[28];
    const float* la_b     = (const float*)d_in[29];
    const float* u1_w     = (const float*)d_in[30];
    const float* u1_b     = (const float*)d_in[31];
    const float* u2_w     = (const float*)d_in[32];
    const float* u2_b     = (const float*)d_in[33];
    const float* u3_w     = (const float*)d_in[34];
    const float* u3_b     = (const float*)d_in[35];
    const float* en_w     = (const float*)d_in[36];
    const float* en_b     = (const float*)d_in[37];
    const float* li_w     = (const float*)d_in[38];
    const float* li_b     = (const float*)d_in[39];
    const float* lj_w     = (const float*)d_in[40];
    const float* lj_b     = (const float*)d_in[41];
    const float* bn_g     = (const float*)d_in[42];
    const float* bn_b     = (const float*)d_in[43];
    const float* ac_w     = (const float*)d_in[44];
    const float* ac_b     = (const float*)d_in[45];
    const float* fl_w     = (const float*)d_in[46];
    const float* fl_b     = (const float*)d_in[47];
    const int*   ei_g     = (const int*)d_in[48];
    const int*   ei_lg    = (const int*)d_in[49];

    const int* s_g  = ei_g;
    const int* d_g  = ei_g + NLG_;
    const int* ls   = ei_lg;
    const int* ldst = ei_lg + ELG_;

    float* ws = (float*)d_ws;
    size_t o = 0;
    float* ub0  = ws + o; o += (size_t)NLG_ * TILE_;
    float* ub1  = ws + o; o += (size_t)NLG_ * TILE_;
    float* hm   = ws + o; o += (size_t)NLG_ * HF_;
    float* hbuf = ws + o; o += (size_t)NG_ * H_;
    float* dgl  = ws + o; o += (size_t)NLG_ * NB_;
    float* egl  = ws + o; o += (size_t)ELG_ * NB_;
    float* p1b  = ws + o; o += (size_t)NG_ * HF_;
    float* p2b  = ws + o; o += (size_t)NG_ * HF_;
    float* q34b = ws + o; o += (size_t)NLG_ * HF_;
    float* rvb  = ws + o; o += (size_t)NLG_ * 32;
    float* csX0 = ws + o; o += (size_t)NLG_ * 32;
    float* csX1 = ws + o; o += (size_t)NLG_ * 32;
    float* ssX0 = ws + o; o += (size_t)NLG_ * 32;
    float* ssX1 = ws + o; o += (size_t)NLG_ * 32;
    float* dsb  = ws + o; o += (size_t)NLG_ * 32;
    float* gtb  = ws + o; o += (size_t)NLG_ * 32;
    float* oac  = ws + o; o += (size_t)G_ * HF_;
    float* bna  = ws + o; o += 256;
    float* dlb  = ws + o; o += (size_t)L_ * NLG_ * 32;
    float* efb  = ws + o; o += (size_t)L_ * ELG_ * 32;
    int*   offsg = (int*)(ws + o); o += G_ * 65;
    int*   csrp  = (int*)(ws + o); o += ELG_;

    float* csX[2] = {csX0, csX1};
    float* ssX[2] = {ssX0, ssX1};

    kA<<<7425, 256, 0, stream>>>(x_g, W_enc, b_enc, ealg, ga_w, ga_b,
                                 x_lg, gd_w, gd_b, eag, W_msg, b_msg,
                                 ls, ldst,
                                 hbuf, egl, dgl, p1b, p2b, q34b,
                                 offsg, csrp, bna);
    kB<<<21504, 256, 0, stream>>>(p1b, p2b, q34b, s_g, d_g, hm,
                                  dgl, egl, ld_w, ld_b, la_w, la_b,
                                  en_w, en_b, dlb, efb);
    kC<<<1152, 256, 0, stream>>>(hm, W_init, b_init, rvb, csX[0], dsb,
                                 np_l1_w, np_l1_b, np_l2_w, np_l2_b,
                                 np_lin_w, np_lin_b, oac);

    float* ubufs[2] = {ub0, ub1};
    for (int i = 0; i < L_; ++i) {
        const float* ui = ubufs[i & 1];
        float* uo = ubufs[(i + 1) & 1];
        int in_ = i & 1, out_ = (i + 1) & 1;
        // gtdl(i): reads cs/ds of u^i, zeros the accumulators k_layer(i) fills
        k_gtdl<<<1024, 256, 0, stream>>>(
            csX[in_], dsb,
            (i > 0 ? bna + (i-1)*64 : bna), bn_g + i*32, bn_b + i*32, i,
            u1_w + i*128, u2_w + i*128, u3_w + i*128,
            u1_b + i*32, u2_b + i*32, u3_b + i*32,
            dlb + (size_t)i*NLG_*32, gtb, csX[out_], ssX[out_]);
        k_layer<<<4096, 256, 0, stream>>>(
            ui, uo, offsg, csrp,
            (i > 0 ? bna + (i-1)*64 : bna), bn_g + i*32, bn_b + i*32, i,
            (i == L_ - 1) ? 1 : 0,
            rvb, b_init,
            u1_w + i*128,
            li_w + i*128, li_b + i*32,
            lj_w + i*128, lj_b + i*32,
            dlb + (size_t)i*NLG_*32, gtb, efb + (size_t)i*ELG_*32,
            csX[out_], ssX[out_], dsb);
        k_midx<<<G_, 256, 0, stream>>>(
            csX[out_], ssX[out_], dsb,
            fe_l1_w, fe_l1_b, fe_l2_w, fe_l2_b, fe_lin_w, fe_lin_b,
            bna + i*64, oac, 1.0f / (float)L_,
            (i == L_ - 1) ? 1 : 0, ac_w, ac_b, fl_w, fl_b, (float*)d_out);
    }
}

// Round 7
// 1360.866 us; speedup vs baseline: 1.0294x; 1.0294x over previous
//
#include <hip/hip_runtime.h>

#define G_    128
#define NV_   32
#define EPG_  64
#define LEPG_ 256
#define NG_   (G_*NV_)      // 4096
#define NLG_  (G_*EPG_)     // 8192
#define ELG_  (G_*LEPG_)    // 32768
#define K_    64
#define H_    32
#define HF_   128
#define L_    4
#define NC_   12
#define FIN_  16
#define FE_   16
#define NB_   4
#define TILE_ (K_*H_)       // 2048

// ---------------------------------------------------------------------------
// Kernel A: init + pre(enc,glob) + p12 + q34 + csr — independent roles by bid
__global__ __launch_bounds__(256) void kA(
    const float* __restrict__ xg, const float* __restrict__ Wenc,
    const float* __restrict__ benc,
    const float* __restrict__ ealg, const float* __restrict__ gaw,
    const float* __restrict__ gab,
    const float* __restrict__ xlg, const float* __restrict__ gdw,
    const float* __restrict__ gdb,
    const float* __restrict__ eag, const float* __restrict__ Wm,
    const float* __restrict__ bm,
    const int* __restrict__ ls, const int* __restrict__ ldst,
    float* __restrict__ h, float* __restrict__ eglob, float* __restrict__ dglob,
    float* __restrict__ p1, float* __restrict__ p2, float* __restrict__ q34,
    int* __restrict__ offsg, int* __restrict__ csrp, float* __restrict__ bna)
{
    __shared__ int cnt[64], offs[65], cur[64];
    int bid = blockIdx.x, t = threadIdx.x;
    if (bid == 0) {
        bna[t] = 0.f;
        return;
    }
    if (bid < 1 + 1152) {
        int lb = bid - 1;
        if (lb < 512) {
            int gid = lb*256 + t; int nn = gid>>5, ch = gid&31;
            float s = benc[ch];
#pragma unroll
            for (int f = 0; f < FIN_; ++f) s += xg[nn*FIN_+f]*Wenc[f*H_+ch];
            h[gid] = s;
        } else {
            int gid = (lb-512)*256 + t;
            if (gid < ELG_*4) {
                int e = gid>>2, k = gid&3;
                float s = gab[k];
#pragma unroll
                for (int j = 0; j < 4; ++j) s += ealg[e*4+j]*gaw[j*4+k];
                eglob[gid] = s;
            } else {
                int gid2 = gid - ELG_*4;
                int nn = gid2>>2, k = gid2&3;
                float s = gdb[k];
#pragma unroll
                for (int j = 0; j < 4; ++j) s += xlg[nn*4+j]*gdw[j*4+k];
                dglob[gid2] = s;
            }
        }
        return;
    }
    if (bid < 1 + 1152 + 2048) {
        int lb = bid - 1153;
        int n = lb*2 + (t>>7), o = t&127;
        // compute h row inline (avoids cross-block dependency within this launch)
        float hv[32];
#pragma unroll
        for (int k = 0; k < 32; ++k) {
            float s = benc[k];
#pragma unroll
            for (int f = 0; f < FIN_; ++f) s += xg[n*FIN_+f]*Wenc[f*H_+k];
            hv[k] = s;
        }
        float a = 0.f, b = 0.f;
#pragma unroll
        for (int k = 0; k < 32; ++k) {
            a += hv[k] * Wm[k*HF_ + o];
            b += hv[k] * Wm[(32+k)*HF_ + o];
        }
        p1[n*HF_ + o] = a; p2[n*HF_ + o] = b;
        return;
    }
    if (bid < 1 + 1152 + 2048 + 4096) {
        int lb = bid - 3201;
        int e = lb*2 + (t>>7), o = t&127;
        float s = bm[o];
#pragma unroll
        for (int k = 0; k < 16; ++k) s += eag[e*16+k] * Wm[(64+k)*HF_ + o];
#pragma unroll
        for (int k = 0; k < 4; ++k)  s += xlg[e*4+k]  * Wm[(80+k)*HF_ + o];
        q34[e*HF_ + o] = s;
        return;
    }
    {   // csr role
        int g = bid - 7297;
        if (t < 64) cnt[t] = 0;
        __syncthreads();
        int d = ldst[g*256 + t] & 63;
        int sl = ls[g*256 + t] & 63;
        atomicAdd(&cnt[d], 1);
        __syncthreads();
        if (t == 0) {
            int a = 0;
            for (int i = 0; i < 64; ++i) { offs[i] = a; a += cnt[i]; }
            offs[64] = a;
        }
        __syncthreads();
        if (t < 64) { cur[t] = offs[t]; offsg[g*65 + t] = offs[t]; }
        if (t == 0) offsg[g*65 + 64] = offs[64];
        __syncthreads();
        int p = atomicAdd(&cur[d], 1);
        csrp[g*256 + p] = (t << 6) | sl;
    }
}

// ---------------------------------------------------------------------------
// Kernel B: msg2 (hm gather-add) + dlef (all layers) — roles by bid
__global__ __launch_bounds__(256) void kB(
    const float* __restrict__ p1, const float* __restrict__ p2,
    const float* __restrict__ q34, const int* __restrict__ sidx,
    const int* __restrict__ didx, float* __restrict__ hm,
    const float* __restrict__ dgl, const float* __restrict__ egl,
    const float* __restrict__ ldw, const float* __restrict__ ldb,
    const float* __restrict__ law, const float* __restrict__ lab,
    const float* __restrict__ enw, const float* __restrict__ enb,
    float* __restrict__ dlb, float* __restrict__ efb)
{
    __shared__ float el[8][32];
    int bid = blockIdx.x, t = threadIdx.x;
    if (bid < 1024) {
        int idx = bid*256 + t;     // NLG*32 float4s
        int e = idx >> 5, o4 = idx & 31;
        int s = sidx[e], d = didx[e];
        float4 a = ((const float4*)p1)[s*32 + o4];
        float4 b = ((const float4*)p2)[d*32 + o4];
        float4 q = ((const float4*)q34)[e*32 + o4];
        ((float4*)hm)[idx] = make_float4(a.x+b.x+q.x, a.y+b.y+q.y, a.z+b.z+q.z, a.w+b.w+q.w);
        return;
    }
    int lb = bid - 1024;
    if (lb < 4096) {
        int gid = lb*256 + t;
        int l = gid >> 18, rem = gid & ((1<<18)-1);
        int n = rem >> 5, ch = rem & 31;
        float s = ldb[l*32 + ch];
#pragma unroll
        for (int j = 0; j < 4; ++j) s += dgl[n*4+j] * ldw[l*128 + j*32 + ch];
        dlb[gid] = s;
    } else {
        int p = (lb - 4096)*8 + (t >> 5);
        int ch = t & 31;
        int l = p >> 15, e = p & 32767;
        float s = lab[l*32 + ch];
#pragma unroll
        for (int j = 0; j < 4; ++j) s += egl[e*4+j] * law[l*128 + j*32 + ch];
        el[t>>5][ch] = s;
        __syncthreads();
        float o = enb[l*32 + ch];
        for (int k = 0; k < 32; ++k) o += el[t>>5][k] * enw[l*1024 + k*32 + ch];
        efb[(size_t)l*ELG_*32 + e*32 + ch] = o;
    }
}

// ---------------------------------------------------------------------------
// Kernel C: rv (+layer-0 cs/ds stats) + out0 — roles by bid
__global__ __launch_bounds__(256) void kC(
    const float* __restrict__ hm, const float* __restrict__ Wi,
    const float* __restrict__ bi, float* __restrict__ rv,
    float* __restrict__ cs, float* __restrict__ ds,
    const float* __restrict__ l1w, const float* __restrict__ l1b,
    const float* __restrict__ l2w, const float* __restrict__ l2b,
    const float* __restrict__ lnw, const float* __restrict__ lnb,
    float* __restrict__ out_acc)
{
    __shared__ float mh[128], o1[128];
    int bid = blockIdx.x, t = threadIdx.x;
    if (bid < 1024) {
        int n = bid*8 + (t>>5), ch = t&31;
        float s = Wi[ch];
        for (int f = 0; f < HF_; ++f) s += hm[n*HF_ + f] * Wi[(1+f)*H_ + ch];
        rv[n*32 + ch] = s;
        cs[n*32 + ch] = 64.f*bi[ch] + s;
        ds[n*32 + ch] = bi[ch] + s;
        return;
    }
    int g = bid - 1024;
    if (t < 128) {
        float s = 0.f;
        for (int k = 0; k < 64; ++k) s += hm[(g*64+k)*HF_ + t];
        mh[t] = s * (1.f/64.f);
    }
    __syncthreads();
    float o = 0.f;
    if (t < 128) {
        o = l1b[t] + l2b[t] + (l1w[t]*(1.f/64.f) + l2w[t]);
        for (int k = 0; k < 128; ++k)
            o += mh[k] * (l1w[(1+k)*HF_ + t]*(1.f/64.f) + l2w[(1+k)*HF_ + t]);
        o1[t] = o;
    }
    __syncthreads();
    if (t < 128) {
        float r = lnb[t];
        for (int k = 0; k < 128; ++k) r += o1[k] * lnw[k*HF_ + t];
        out_acc[g*HF_ + t] = o + (r > 0.f ? r : 0.f);
    }
}

// gtdl for one layer (BN fold inline from bna) + zero next stats accumulators
__global__ __launch_bounds__(256) void k_gtdl(
    const float* __restrict__ cs, const float* __restrict__ ds,
    const float* __restrict__ bnaP, const float* __restrict__ bng,
    const float* __restrict__ bnb, int lay,
    const float* __restrict__ u1w, const float* __restrict__ u2w,
    const float* __restrict__ u3w, const float* __restrict__ u1b,
    const float* __restrict__ u2b, const float* __restrict__ u3b,
    const float* __restrict__ dl_l, float* __restrict__ gtb,
    float* __restrict__ csZ, float* __restrict__ ssZ) {
    int idx = blockIdx.x*256 + threadIdx.x;
    int n = idx >> 5, ch = idx & 31;
    int chi = ch & 3, twb = ch & ~3;
    float gt = u1b[ch] + u2b[ch] + u3b[ch];
#pragma unroll
    for (int j = 0; j < 4; ++j) {
        int bj = twb + j;
        float s_ = 1.f, sh_ = 0.f;
        if (lay > 0) {
            float m = bnaP[bj] * (1.f/524288.f);
            float v = bnaP[32+bj] * (1.f/524288.f) - m*m;
            s_ = bng[bj] * rsqrtf(v + 1e-5f);
            sh_ = bnb[bj] - m*s_;
        }
        float csF = s_*cs[n*32 + bj] + 64.f*sh_;
        float dgF = s_*ds[n*32 + bj] + sh_;
        gt += csF*(1.f/64.f)*u2w[bj*4 + chi] + dgF*u3w[bj*4 + chi]
            + sh_*u1w[bj*4 + chi];
    }
    gtb[idx] = gt * dl_l[idx];
    csZ[idx] = 0.f;
    ssZ[idx] = 0.f;
}

// ---------------------------------------------------------------------------
// main layer kernel: 256 threads, block = (graph, 2-color chunk).
// um in LDS (16KB); own u in regs. launch_bounds(256,4): VGPR cap 128 — the
// round-5/6 spill disaster came from capping at ~85 with ~100 live regs.
#define UM_NODE(I, UOI)                                                     \
  {                                                                         \
    float4 dl = *(const float4*)(dl_l + (((size_t)(n0g+I))<<5) + chb);      \
    float4 gt = *(const float4*)(gtb  + (((size_t)(n0g+I))<<5) + chb);      \
    float m0 = (UOI.x*w1f[0]+UOI.y*w1f[4]+UOI.z*w1f[8] +UOI.w*w1f[12])*dl.x + gt.x; \
    float m1 = (UOI.x*w1f[1]+UOI.y*w1f[5]+UOI.z*w1f[9] +UOI.w*w1f[13])*dl.y + gt.y; \
    float m2 = (UOI.x*w1f[2]+UOI.y*w1f[6]+UOI.z*w1f[10]+UOI.w*w1f[14])*dl.z + gt.z; \
    float m3 = (UOI.x*w1f[3]+UOI.y*w1f[7]+UOI.z*w1f[11]+UOI.w*w1f[15])*dl.w + gt.w; \
    *(float4*)&um[(nq*4+I)*64 + coff] = make_float4(m0,m1,m2,m3);           \
  }

#define EDGE_UN_NODE(I, UOI)                                                \
  {                                                                         \
    const int nI = nq*4 + I;                                                \
    float4 mo = *(float4*)&um[nI*64 + coff];                                \
    float4 ui;                                                              \
    ui.x = bli4[0] + mo.x*wi[0] + mo.y*wi[4] + mo.z*wi[8]  + mo.w*wi[12];   \
    ui.y = bli4[1] + mo.x*wi[1] + mo.y*wi[5] + mo.z*wi[9]  + mo.w*wi[13];   \
    ui.z = bli4[2] + mo.x*wi[2] + mo.y*wi[6] + mo.z*wi[10] + mo.w*wi[14];   \
    ui.w = bli4[3] + mo.x*wi[3] + mo.y*wi[7] + mo.z*wi[11] + mo.w*wi[15];   \
    float4 acc = make_float4(0.f,0.f,0.f,0.f);                              \
    const int je = offs[nI+1];                                              \
    for (int j = offs[nI]; j < je; ++j) {                                   \
        int pk = ep[j];                                                     \
        float4 ef4 = *(const float4*)(ef_l + (((size_t)((g<<8)+(pk>>6)))<<5) + chb); \
        float4 u4 = *(float4*)&um[(pk & 63)*64 + coff];                     \
        float r0 = ui.x + ef4.x + blj4[0] + u4.x*wj[0] + u4.y*wj[4] + u4.z*wj[8]  + u4.w*wj[12]; \
        float r1 = ui.y + ef4.y + blj4[1] + u4.x*wj[1] + u4.y*wj[5] + u4.z*wj[9]  + u4.w*wj[13]; \
        float r2 = ui.z + ef4.z + blj4[2] + u4.x*wj[2] + u4.y*wj[6] + u4.z*wj[10] + u4.w*wj[14]; \
        float r3 = ui.w + ef4.w + blj4[3] + u4.x*wj[3] + u4.y*wj[7] + u4.z*wj[11] + u4.w*wj[15]; \
        acc.x += u4.x + (r0>0.f?r0:0.f);                                    \
        acc.y += u4.y + (r1>0.f?r1:0.f);                                    \
        acc.z += u4.z + (r2>0.f?r2:0.f);                                    \
        acc.w += u4.w + (r3>0.f?r3:0.f);                                    \
    }                                                                       \
    float4 un4;                                                             \
    un4.x = acc.x*0.25f + sc4[0]*UOI.x + sh4[0];                            \
    un4.y = acc.y*0.25f + sc4[1]*UOI.y + sh4[1];                            \
    un4.z = acc.z*0.25f + sc4[2]*UOI.z + sh4[2];                            \
    un4.w = acc.w*0.25f + sc4[3]*UOI.w + sh4[3];                            \
    if (!last)                                                              \
        *(float4*)(u_out + (((size_t)(n0g+I))<<11) + (ck<<6) + coff) = un4; \
    if (col0 == nI)                                                         \
        *(float4*)&dsb[(((size_t)(n0g+I))<<5) + chb] = un4;                 \
    float cx=un4.x, cy=un4.y, cz=un4.z, cw=un4.w;                           \
    float qx=cx*cx, qy=cy*cy, qz=cz*cz, qw=cw*cw;                           \
    cx+=__shfl_xor(cx,8); cy+=__shfl_xor(cy,8); cz+=__shfl_xor(cz,8); cw+=__shfl_xor(cw,8); \
    qx+=__shfl_xor(qx,8); qy+=__shfl_xor(qy,8); qz+=__shfl_xor(qz,8); qw+=__shfl_xor(qw,8); \
    int nb32 = ((n0g+I) << 5) + chb;                                        \
    if (c == 0) {                                                           \
        atomicAdd(&csO[nb32+0], cx); atomicAdd(&csO[nb32+1], cy);           \
        atomicAdd(&csO[nb32+2], cz); atomicAdd(&csO[nb32+3], cw);           \
    } else {                                                                \
        atomicAdd(&ssO[nb32+0], qx); atomicAdd(&ssO[nb32+1], qy);           \
        atomicAdd(&ssO[nb32+2], qz); atomicAdd(&ssO[nb32+3], qw);           \
    }                                                                       \
  }

__global__ __launch_bounds__(256, 4) void k_layer(
    const float* __restrict__ u_in, float* __restrict__ u_out,
    const int* __restrict__ offsg, const int* __restrict__ csrp,
    const float* __restrict__ bnaP, const float* __restrict__ bng,
    const float* __restrict__ bnb, int lay, int last,
    const float* __restrict__ rvb, const float* __restrict__ bi,
    const float* __restrict__ u1w,
    const float* __restrict__ liw, const float* __restrict__ lib,
    const float* __restrict__ ljw, const float* __restrict__ ljb,
    const float* __restrict__ dl_l, const float* __restrict__ gtb,
    const float* __restrict__ ef_l,
    float* __restrict__ csO, float* __restrict__ ssO, float* __restrict__ dsb)
{
    __shared__ float um[64*64];     // 16 KB
    __shared__ int ep[256];
    __shared__ int offs[65];

    const int bid = blockIdx.x, t = threadIdx.x;
    const int g  = ((bid >> 8) << 3) | (bid & 7);   // XCD swizzle, 4096%8==0
    const int ck = (bid >> 3) & 31;                 // 2-color chunk
    const int tw = t & 7, c = (t >> 3) & 1, nq = t >> 4;   // nq in [0,16)
    const int chb = tw * 4;
    const int coff = c*32 + chb;                    // [0,64)
    const int n0g = g*64 + nq*4;
    const int col0 = ck*2 + c;                      // this thread's global color

    ep[t] = csrp[g*256 + t];
    if (t < 65) offs[t] = offsg[g*65 + t];

    // own u (registers)
    float4 uo0, uo1, uo2, uo3;
    if (lay == 0) {
        float4 b4 = *(const float4*)(bi + chb);
        uo0 = b4; uo1 = b4; uo2 = b4; uo3 = b4;
        int d = col0 - nq*4;
        if (d >= 0 && d < 4) {
            float4 r = *(const float4*)(rvb + (size_t)(n0g + d)*32 + chb);
            if      (d == 0) { uo0.x+=r.x; uo0.y+=r.y; uo0.z+=r.z; uo0.w+=r.w; }
            else if (d == 1) { uo1.x+=r.x; uo1.y+=r.y; uo1.z+=r.z; uo1.w+=r.w; }
            else if (d == 2) { uo2.x+=r.x; uo2.y+=r.y; uo2.z+=r.z; uo2.w+=r.w; }
            else             { uo3.x+=r.x; uo3.y+=r.y; uo3.z+=r.z; uo3.w+=r.w; }
        }
    } else {
        const float* ub = u_in + ((size_t)n0g << 11) + (ck << 6) + coff;
        uo0 = *(const float4*)(ub);
        uo1 = *(const float4*)(ub + 2048);
        uo2 = *(const float4*)(ub + 4096);
        uo3 = *(const float4*)(ub + 6144);
    }

    // BN fold
    float sc4[4], sh4[4];
    if (lay > 0) {
#pragma unroll
        for (int j2 = 0; j2 < 4; ++j2) {
            int bj = chb + j2;
            float m = bnaP[bj] * (1.f/524288.f);
            float v = bnaP[32+bj] * (1.f/524288.f) - m*m;
            float s_ = bng[bj] * rsqrtf(v + 1e-5f);
            sc4[j2] = s_; sh4[j2] = bnb[bj] - m*s_;
        }
    } else {
#pragma unroll
        for (int j2 = 0; j2 < 4; ++j2) { sc4[j2] = 1.f; sh4[j2] = 0.f; }
    }
    // weights (w1f dies at barrier; wi/wj live through edge phase)
    float wi[16], wj[16], bli4[4], blj4[4];
#pragma unroll
    for (int j2 = 0; j2 < 4; ++j2)
#pragma unroll
        for (int d = 0; d < 4; ++d) {
            wi[j2*4+d] = liw[(chb+j2)*4 + d];
            wj[j2*4+d] = ljw[(chb+j2)*4 + d];
        }
#pragma unroll
    for (int d = 0; d < 4; ++d) { bli4[d] = lib[chb+d]; blj4[d] = ljb[chb+d]; }

    {
        float w1f[16];
#pragma unroll
        for (int j2 = 0; j2 < 4; ++j2)
#pragma unroll
            for (int d = 0; d < 4; ++d)
                w1f[j2*4+d] = u1w[(chb+j2)*4 + d] * sc4[j2];
        UM_NODE(0, uo0)
        UM_NODE(1, uo1)
        UM_NODE(2, uo2)
        UM_NODE(3, uo3)
    }
    __syncthreads();

    EDGE_UN_NODE(0, uo0)
    EDGE_UN_NODE(1, uo1)
    EDGE_UN_NODE(2, uo2)
    EDGE_UN_NODE(3, uo3)
}

// per-graph reduce of cs/ss/ds + bn accumulation + graph extract (+final head)
__global__ __launch_bounds__(256) void k_midx(
    const float* __restrict__ cs, const float* __restrict__ ss,
    const float* __restrict__ ds,
    const float* __restrict__ l1w, const float* __restrict__ l1b,
    const float* __restrict__ l2w, const float* __restrict__ l2b,
    const float* __restrict__ lnw, const float* __restrict__ lnb,
    float* __restrict__ bna_i, float* __restrict__ out_acc, float scale,
    int do_final, const float* __restrict__ acw, const float* __restrict__ acb,
    const float* __restrict__ flw, const float* __restrict__ flb,
    float* __restrict__ outp)
{
    __shared__ float red[3*128];
    __shared__ float S[32], D[32], o1[128], ov[128], t1[128];
    int g = blockIdx.x, t = threadIdx.x;
    int ch = t & 31, ng = t >> 5;
    float pS = 0.f, pQ = 0.f, pD = 0.f;
#pragma unroll
    for (int k = 0; k < 8; ++k) {
        int n = g*64 + ng*8 + k;
        pS += cs[n*32 + ch];
        pQ += ss[n*32 + ch];
        pD += ds[n*32 + ch];
    }
    pS += __shfl_xor(pS, 32); pQ += __shfl_xor(pQ, 32); pD += __shfl_xor(pD, 32);
    int w = t >> 6;
    if ((t & 63) < 32) {
        red[w*32 + ch] = pS;
        red[128 + w*32 + ch] = pQ;
        red[256 + w*32 + ch] = pD;
    }
    __syncthreads();
    if (t < 32) {
        float S_ = 0.f, Q_ = 0.f, D_ = 0.f;
#pragma unroll
        for (int ww = 0; ww < 4; ++ww) {
            S_ += red[ww*32 + t]; Q_ += red[128 + ww*32 + t]; D_ += red[256 + ww*32 + t];
        }
        S[t] = S_; D[t] = D_;
        atomicAdd(&bna_i[t], S_);
        atomicAdd(&bna_i[32 + t], Q_);
    }
    __syncthreads();
    float o = 0.f;
    if (t < 128) {
        o = l1b[t] + l2b[t];
        for (int k = 0; k < 32; ++k)
            o += (S[k]*(1.f/4096.f))*l1w[k*HF_ + t] + (D[k]*(1.f/64.f))*l2w[k*HF_ + t];
        o1[t] = o;
    }
    __syncthreads();
    if (t < 128) {
        float r = lnb[t];
        for (int k = 0; k < 128; ++k) r += o1[k] * lnw[k*HF_ + t];
        float newv = out_acc[g*HF_ + t] + (o + (r > 0.f ? r : 0.f)) * scale;
        out_acc[g*HF_ + t] = newv;
        ov[t] = newv;
    }
    if (do_final) {
        __syncthreads();
        if (t < 128) {
            float r2 = acb[t];
            for (int k = 0; k < 128; ++k) r2 += ov[k] * acw[k*HF_ + t];
            t1[t] = ov[t] + (r2 > 0.f ? r2 : 0.f);
        }
        __syncthreads();
        if (t < NC_) {
            float s2 = flb[t];
            for (int k = 0; k < 128; ++k) s2 += t1[k] * flw[k*NC_ + t];
            outp[g*NC_ + t] = s2;
        }
    }
}

// ---------------------------------------------------------------------------
extern "C" void kernel_launch(void* const* d_in, const int* in_sizes, int n_in,
                              void* d_out, int out_size, void* d_ws, size_t ws_size,
                              hipStream_t stream) {
    const float* x_g      = (const float*)d_in[0];
    const float* eag      = (const float*)d_in[1];
    const float* x_lg     = (const float*)d_in[2];
    const float* ealg     = (const float*)d_in[3];
    const float* W_enc    = (const float*)d_in[4];
    const float* b_enc    = (const float*)d_in[5];
    const float* W_msg    = (const float*)d_in[6];
    const float* b_msg    = (const float*)d_in[7];
    const float* W_init   = (const float*)d_in[8];
    const float* b_init   = (const float*)d_in[9];
    const float* np_l1_w  = (const float*)d_in[10];
    const float* np_l1_b  = (const float*)d_in[11];
    const float* np_l2_w  = (const float*)d_in[12];
    const float* np_l2_b  = (const float*)d_in[13];
    const float* np_lin_w = (const float*)d_in[14];
    const float* np_lin_b = (const float*)d_in[15];
    const float* fe_l1_w  = (const float*)d_in[16];
    const float* fe_l1_b  = (const float*)d_in[17];
    const float* fe_l2_w  = (const float*)d_in[18];
    const float* fe_l2_b  = (const float*)d_in[19];
    const float* fe_lin_w = (const float*)d_in[20];
    const float* fe_lin_b = (const float*)d_in[21];
    const float* gd_w     = (const float*)d_in[22];
    const float* gd_b     = (const float*)d_in[23];
    const float* ga_w     = (const float*)d_in[24];
    const float* ga_b     = (const float*)d_in[25];
    const float* ld_w     = (const float*)d_in[26];
    const float* ld_b     = (const float*)d_in[27];
    const float* la_w     = (const float*)d_in[28];
    const float* la_b     = (const float*)d_in[29];
    const float* u1_w     = (const float*)d_in[30];
    const float* u1_b     = (const float*)d_in[31];
    const float* u2_w     = (const float*)d_in[32];
    const float* u2_b     = (const float*)d_in[33];
    const float* u3_w     = (const float*)d_in[34];
    const float* u3_b     = (const float*)d_in[35];
    const float* en_w     = (const float*)d_in[36];
    const float* en_b     = (const float*)d_in[37];
    const float* li_w     = (const float*)d_in[38];
    const float* li_b     = (const float*)d_in[39];
    const float* lj_w     = (const float*)d_in[40];
    const float* lj_b     = (const float*)d_in[41];
    const float* bn_g     = (const float*)d_in[42];
    const float* bn_b     = (const float*)d_in[43];
    const float* ac_w     = (const float*)d_in[44];
    const float* ac_b     = (const float*)d_in[45];
    const float* fl_w     = (const float*)d_in[46];
    const float* fl_b     = (const float*)d_in[47];
    const int*   ei_g     = (const int*)d_in[48];
    const int*   ei_lg    = (const int*)d_in[49];

    const int* s_g  = ei_g;
    const int* d_g  = ei_g + NLG_;
    const int* ls   = ei_lg;
    const int* ldst = ei_lg + ELG_;

    float* ws = (float*)d_ws;
    size_t o = 0;
    float* ub0  = ws + o; o += (size_t)NLG_ * TILE_;
    float* ub1  = ws + o; o += (size_t)NLG_ * TILE_;
    float* hm   = ws + o; o += (size_t)NLG_ * HF_;
    float* hbuf = ws + o; o += (size_t)NG_ * H_;
    float* dgl  = ws + o; o += (size_t)NLG_ * NB_;
    float* egl  = ws + o; o += (size_t)ELG_ * NB_;
    float* p1b  = ws + o; o += (size_t)NG_ * HF_;
    float* p2b  = ws + o; o += (size_t)NG_ * HF_;
    float* q34b = ws + o; o += (size_t)NLG_ * HF_;
    float* rvb  = ws + o; o += (size_t)NLG_ * 32;
    float* csX0 = ws + o; o += (size_t)NLG_ * 32;
    float* csX1 = ws + o; o += (size_t)NLG_ * 32;
    float* ssX0 = ws + o; o += (size_t)NLG_ * 32;
    float* ssX1 = ws + o; o += (size_t)NLG_ * 32;
    float* dsb  = ws + o; o += (size_t)NLG_ * 32;
    float* gtb  = ws + o; o += (size_t)NLG_ * 32;
    float* oac  = ws + o; o += (size_t)G_ * HF_;
    float* bna  = ws + o; o += 256;
    float* dlb  = ws + o; o += (size_t)L_ * NLG_ * 32;
    float* efb  = ws + o; o += (size_t)L_ * ELG_ * 32;
    int*   offsg = (int*)(ws + o); o += G_ * 65;
    int*   csrp  = (int*)(ws + o); o += ELG_;

    float* csX[2] = {csX0, csX1};
    float* ssX[2] = {ssX0, ssX1};

    kA<<<7425, 256, 0, stream>>>(x_g, W_enc, b_enc, ealg, ga_w, ga_b,
                                 x_lg, gd_w, gd_b, eag, W_msg, b_msg,
                                 ls, ldst,
                                 hbuf, egl, dgl, p1b, p2b, q34b,
                                 offsg, csrp, bna);
    kB<<<21504, 256, 0, stream>>>(p1b, p2b, q34b, s_g, d_g, hm,
                                  dgl, egl, ld_w, ld_b, la_w, la_b,
                                  en_w, en_b, dlb, efb);
    kC<<<1152, 256, 0, stream>>>(hm, W_init, b_init, rvb, csX[0], dsb,
                                 np_l1_w, np_l1_b, np_l2_w, np_l2_b,
                                 np_lin_w, np_lin_b, oac);

    float* ubufs[2] = {ub0, ub1};
    for (int i = 0; i < L_; ++i) {
        const float* ui = ubufs[i & 1];
        float* uo = ubufs[(i + 1) & 1];
        int in_ = i & 1, out_ = (i + 1) & 1;
        // gtdl(i): reads cs/ds of u^i, zeros the accumulators k_layer(i) fills
        k_gtdl<<<1024, 256, 0, stream>>>(
            csX[in_], dsb,
            (i > 0 ? bna + (i-1)*64 : bna), bn_g + i*32, bn_b + i*32, i,
            u1_w + i*128, u2_w + i*128, u3_w + i*128,
            u1_b + i*32, u2_b + i*32, u3_b + i*32,
            dlb + (size_t)i*NLG_*32, gtb, csX[out_], ssX[out_]);
        k_layer<<<4096, 256, 0, stream>>>(
            ui, uo, offsg, csrp,
            (i > 0 ? bna + (i-1)*64 : bna), bn_g + i*32, bn_b + i*32, i,
            (i == L_ - 1) ? 1 : 0,
            rvb, b_init,
            u1_w + i*128,
            li_w + i*128, li_b + i*32,
            lj_w + i*128, lj_b + i*32,
            dlb + (size_t)i*NLG_*32, gtb, efb + (size_t)i*ELG_*32,
            csX[out_], ssX[out_], dsb);
        k_midx<<<G_, 256, 0, stream>>>(
            csX[out_], ssX[out_], dsb,
            fe_l1_w, fe_l1_b, fe_l2_w, fe_l2_b, fe_lin_w, fe_lin_b,
            bna + i*64, oac, 1.0f / (float)L_,
            (i == L_ - 1) ? 1 : 0, ac_w, ac_b, fl_w, fl_b, (float*)d_out);
    }
}

// Round 8
// 575.386 us; speedup vs baseline: 2.4347x; 2.3651x over previous
//
#include <hip/hip_runtime.h>

#define G_    128
#define NV_   32
#define EPG_  64
#define LEPG_ 256
#define NG_   (G_*NV_)      // 4096
#define NLG_  (G_*EPG_)     // 8192
#define ELG_  (G_*LEPG_)    // 32768
#define K_    64
#define H_    32
#define HF_   128
#define L_    4
#define NC_   12
#define FIN_  16
#define FE_   16
#define NB_   4
#define TILE_ (K_*H_)       // 2048

// ---------------------------------------------------------------------------
// Kernel A: init + pre(enc,glob) + p12 + q34 + csr — independent roles by bid
__global__ __launch_bounds__(256) void kA(
    const float* __restrict__ xg, const float* __restrict__ Wenc,
    const float* __restrict__ benc,
    const float* __restrict__ ealg, const float* __restrict__ gaw,
    const float* __restrict__ gab,
    const float* __restrict__ xlg, const float* __restrict__ gdw,
    const float* __restrict__ gdb,
    const float* __restrict__ eag, const float* __restrict__ Wm,
    const float* __restrict__ bm,
    const int* __restrict__ ls, const int* __restrict__ ldst,
    float* __restrict__ h, float* __restrict__ eglob, float* __restrict__ dglob,
    float* __restrict__ p1, float* __restrict__ p2, float* __restrict__ q34,
    int* __restrict__ offsg, int* __restrict__ csrp, float* __restrict__ bna)
{
    __shared__ int cnt[64], offs[65], cur[64];
    int bid = blockIdx.x, t = threadIdx.x;
    if (bid == 0) {
        bna[t] = 0.f;
        return;
    }
    if (bid < 1 + 1152) {
        int lb = bid - 1;
        if (lb < 512) {
            int gid = lb*256 + t; int nn = gid>>5, ch = gid&31;
            float s = benc[ch];
#pragma unroll
            for (int f = 0; f < FIN_; ++f) s += xg[nn*FIN_+f]*Wenc[f*H_+ch];
            h[gid] = s;
        } else {
            int gid = (lb-512)*256 + t;
            if (gid < ELG_*4) {
                int e = gid>>2, k = gid&3;
                float s = gab[k];
#pragma unroll
                for (int j = 0; j < 4; ++j) s += ealg[e*4+j]*gaw[j*4+k];
                eglob[gid] = s;
            } else {
                int gid2 = gid - ELG_*4;
                int nn = gid2>>2, k = gid2&3;
                float s = gdb[k];
#pragma unroll
                for (int j = 0; j < 4; ++j) s += xlg[nn*4+j]*gdw[j*4+k];
                dglob[gid2] = s;
            }
        }
        return;
    }
    if (bid < 1 + 1152 + 2048) {
        int lb = bid - 1153;
        int n = lb*2 + (t>>7), o = t&127;
        float hv[32];
#pragma unroll
        for (int k = 0; k < 32; ++k) {
            float s = benc[k];
#pragma unroll
            for (int f = 0; f < FIN_; ++f) s += xg[n*FIN_+f]*Wenc[f*H_+k];
            hv[k] = s;
        }
        float a = 0.f, b = 0.f;
#pragma unroll
        for (int k = 0; k < 32; ++k) {
            a += hv[k] * Wm[k*HF_ + o];
            b += hv[k] * Wm[(32+k)*HF_ + o];
        }
        p1[n*HF_ + o] = a; p2[n*HF_ + o] = b;
        return;
    }
    if (bid < 1 + 1152 + 2048 + 4096) {
        int lb = bid - 3201;
        int e = lb*2 + (t>>7), o = t&127;
        float s = bm[o];
#pragma unroll
        for (int k = 0; k < 16; ++k) s += eag[e*16+k] * Wm[(64+k)*HF_ + o];
#pragma unroll
        for (int k = 0; k < 4; ++k)  s += xlg[e*4+k]  * Wm[(80+k)*HF_ + o];
        q34[e*HF_ + o] = s;
        return;
    }
    {   // csr role
        int g = bid - 7297;
        if (t < 64) cnt[t] = 0;
        __syncthreads();
        int d = ldst[g*256 + t] & 63;
        int sl = ls[g*256 + t] & 63;
        atomicAdd(&cnt[d], 1);
        __syncthreads();
        if (t == 0) {
            int a = 0;
            for (int i = 0; i < 64; ++i) { offs[i] = a; a += cnt[i]; }
            offs[64] = a;
        }
        __syncthreads();
        if (t < 64) { cur[t] = offs[t]; offsg[g*65 + t] = offs[t]; }
        if (t == 0) offsg[g*65 + 64] = offs[64];
        __syncthreads();
        int p = atomicAdd(&cur[d], 1);
        csrp[g*256 + p] = (t << 6) | sl;
    }
}

// ---------------------------------------------------------------------------
// Kernel B: msg2 (hm gather-add) + dlef (all layers) — roles by bid
__global__ __launch_bounds__(256) void kB(
    const float* __restrict__ p1, const float* __restrict__ p2,
    const float* __restrict__ q34, const int* __restrict__ sidx,
    const int* __restrict__ didx, float* __restrict__ hm,
    const float* __restrict__ dgl, const float* __restrict__ egl,
    const float* __restrict__ ldw, const float* __restrict__ ldb,
    const float* __restrict__ law, const float* __restrict__ lab,
    const float* __restrict__ enw, const float* __restrict__ enb,
    float* __restrict__ dlb, float* __restrict__ efb)
{
    __shared__ float el[8][32];
    int bid = blockIdx.x, t = threadIdx.x;
    if (bid < 1024) {
        int idx = bid*256 + t;     // NLG*32 float4s
        int e = idx >> 5, o4 = idx & 31;
        int s = sidx[e], d = didx[e];
        float4 a = ((const float4*)p1)[s*32 + o4];
        float4 b = ((const float4*)p2)[d*32 + o4];
        float4 q = ((const float4*)q34)[e*32 + o4];
        ((float4*)hm)[idx] = make_float4(a.x+b.x+q.x, a.y+b.y+q.y, a.z+b.z+q.z, a.w+b.w+q.w);
        return;
    }
    int lb = bid - 1024;
    if (lb < 4096) {
        int gid = lb*256 + t;
        int l = gid >> 18, rem = gid & ((1<<18)-1);
        int n = rem >> 5, ch = rem & 31;
        float s = ldb[l*32 + ch];
#pragma unroll
        for (int j = 0; j < 4; ++j) s += dgl[n*4+j] * ldw[l*128 + j*32 + ch];
        dlb[gid] = s;
    } else {
        int p = (lb - 4096)*8 + (t >> 5);
        int ch = t & 31;
        int l = p >> 15, e = p & 32767;
        float s = lab[l*32 + ch];
#pragma unroll
        for (int j = 0; j < 4; ++j) s += egl[e*4+j] * law[l*128 + j*32 + ch];
        el[t>>5][ch] = s;
        __syncthreads();
        float o = enb[l*32 + ch];
        for (int k = 0; k < 32; ++k) o += el[t>>5][k] * enw[l*1024 + k*32 + ch];
        efb[(size_t)l*ELG_*32 + e*32 + ch] = o;
    }
}

// ---------------------------------------------------------------------------
// Kernel C: rv (+layer-0 cs/ds stats) + out0 — roles by bid
__global__ __launch_bounds__(256) void kC(
    const float* __restrict__ hm, const float* __restrict__ Wi,
    const float* __restrict__ bi, float* __restrict__ rv,
    float* __restrict__ cs, float* __restrict__ ds,
    const float* __restrict__ l1w, const float* __restrict__ l1b,
    const float* __restrict__ l2w, const float* __restrict__ l2b,
    const float* __restrict__ lnw, const float* __restrict__ lnb,
    float* __restrict__ out_acc)
{
    __shared__ float mh[128], o1[128];
    int bid = blockIdx.x, t = threadIdx.x;
    if (bid < 1024) {
        int n = bid*8 + (t>>5), ch = t&31;
        float s = Wi[ch];
        for (int f = 0; f < HF_; ++f) s += hm[n*HF_ + f] * Wi[(1+f)*H_ + ch];
        rv[n*32 + ch] = s;
        cs[n*32 + ch] = 64.f*bi[ch] + s;
        ds[n*32 + ch] = bi[ch] + s;
        return;
    }
    int g = bid - 1024;
    if (t < 128) {
        float s = 0.f;
        for (int k = 0; k < 64; ++k) s += hm[(g*64+k)*HF_ + t];
        mh[t] = s * (1.f/64.f);
    }
    __syncthreads();
    float o = 0.f;
    if (t < 128) {
        o = l1b[t] + l2b[t] + (l1w[t]*(1.f/64.f) + l2w[t]);
        for (int k = 0; k < 128; ++k)
            o += mh[k] * (l1w[(1+k)*HF_ + t]*(1.f/64.f) + l2w[(1+k)*HF_ + t]);
        o1[t] = o;
    }
    __syncthreads();
    if (t < 128) {
        float r = lnb[t];
        for (int k = 0; k < 128; ++k) r += o1[k] * lnw[k*HF_ + t];
        out_acc[g*HF_ + t] = o + (r > 0.f ? r : 0.f);
    }
}

// gtdl[n][ch] for one layer (BN fold inline from bna)
__global__ __launch_bounds__(256) void k_gtdl(
    const float* __restrict__ cs, const float* __restrict__ ds,
    const float* __restrict__ bnaP, const float* __restrict__ bng,
    const float* __restrict__ bnb, int lay,
    const float* __restrict__ u1w, const float* __restrict__ u2w,
    const float* __restrict__ u3w, const float* __restrict__ u1b,
    const float* __restrict__ u2b, const float* __restrict__ u3b,
    const float* __restrict__ dl_l, float* __restrict__ gtb) {
    int idx = blockIdx.x*256 + threadIdx.x;
    int n = idx >> 5, ch = idx & 31;
    int chi = ch & 3, twb = ch & ~3;
    float gt = u1b[ch] + u2b[ch] + u3b[ch];
#pragma unroll
    for (int j = 0; j < 4; ++j) {
        int bj = twb + j;
        float s_ = 1.f, sh_ = 0.f;
        if (lay > 0) {
            float m = bnaP[bj] * (1.f/524288.f);
            float v = bnaP[32+bj] * (1.f/524288.f) - m*m;
            s_ = bng[bj] * rsqrtf(v + 1e-5f);
            sh_ = bnb[bj] - m*s_;
        }
        float csF = s_*cs[n*32 + bj] + 64.f*sh_;
        float dgF = s_*ds[n*32 + bj] + sh_;
        gt += csF*(1.f/64.f)*u2w[bj*4 + chi] + dgF*u3w[bj*4 + chi]
            + sh_*u1w[bj*4 + chi];
    }
    gtb[idx] = gt * dl_l[idx];
}

// ---------------------------------------------------------------------------
// main layer kernel — ROUND-4 structure verbatim (512 thr, us+um in LDS,
// launch_bounds(512,4) => VGPR cap 128, proven 64-VGPR codegen), plus:
// lay-0 synth staging, last-layer store skip.
#define PROC_NODE(ACC, UI, JE)                                              \
  for (; j < (JE); ++j) {                                                   \
    int jn = j + 2; jn = jn < 255 ? jn : 255;                               \
    int pkN = ep[jn];                                                       \
    float4 efN = *(const float4*)(ef_l + (((size_t)((g<<8)+(pkN>>6)))<<5) + chb); \
    int src = pkA & 63;                                                     \
    float4 u4 = *(float4*)&um[src*128 + coff];                              \
    float r0 = UI.x + efA.x + blj4[0] + u4.x*wj[0] + u4.y*wj[4] + u4.z*wj[8] + u4.w*wj[12]; \
    float r1 = UI.y + efA.y + blj4[1] + u4.x*wj[1] + u4.y*wj[5] + u4.z*wj[9] + u4.w*wj[13]; \
    float r2 = UI.z + efA.z + blj4[2] + u4.x*wj[2] + u4.y*wj[6] + u4.z*wj[10] + u4.w*wj[14]; \
    float r3 = UI.w + efA.w + blj4[3] + u4.x*wj[3] + u4.y*wj[7] + u4.z*wj[11] + u4.w*wj[15]; \
    ACC.x += u4.x + (r0>0.f?r0:0.f);                                        \
    ACC.y += u4.y + (r1>0.f?r1:0.f);                                        \
    ACC.z += u4.z + (r2>0.f?r2:0.f);                                        \
    ACC.w += u4.w + (r3>0.f?r3:0.f);                                        \
    pkA = pkB; efA = efB; pkB = pkN; efB = efN;                             \
  }

#define UM_NODE(I, UIOUT, DL, GT)                                           \
  {                                                                         \
    int nl = nq*4 + I;                                                      \
    float4 uv = *(float4*)&us[nl*128 + coff];                               \
    float m0 = (uv.x*w1f[0]+uv.y*w1f[4]+uv.z*w1f[8] +uv.w*w1f[12])*DL.x + GT.x; \
    float m1 = (uv.x*w1f[1]+uv.y*w1f[5]+uv.z*w1f[9] +uv.w*w1f[13])*DL.y + GT.y; \
    float m2 = (uv.x*w1f[2]+uv.y*w1f[6]+uv.z*w1f[10]+uv.w*w1f[14])*DL.z + GT.z; \
    float m3 = (uv.x*w1f[3]+uv.y*w1f[7]+uv.z*w1f[11]+uv.w*w1f[15])*DL.w + GT.w; \
    *(float4*)&um[nl*128 + coff] = make_float4(m0,m1,m2,m3);                \
    UIOUT.x = bli4[0] + m0*wi[0] + m1*wi[4] + m2*wi[8]  + m3*wi[12];        \
    UIOUT.y = bli4[1] + m0*wi[1] + m1*wi[5] + m2*wi[9]  + m3*wi[13];        \
    UIOUT.z = bli4[2] + m0*wi[2] + m1*wi[6] + m2*wi[10] + m3*wi[14];        \
    UIOUT.w = bli4[3] + m0*wi[3] + m1*wi[7] + m2*wi[11] + m3*wi[15];        \
  }

#define UN_NODE(I, ACC)                                                     \
  {                                                                         \
    float4 uo4 = *(float4*)&us[(nq*4+I)*128 + coff];                        \
    float4 un4;                                                             \
    un4.x = ACC.x*0.25f + sc4[0]*uo4.x + sh4[0];                            \
    un4.y = ACC.y*0.25f + sc4[1]*uo4.y + sh4[1];                            \
    un4.z = ACC.z*0.25f + sc4[2]*uo4.z + sh4[2];                            \
    un4.w = ACC.w*0.25f + sc4[3]*uo4.w + sh4[3];                            \
    if (!last)                                                              \
        *(float4*)(u_out + (((size_t)(n0g+I))<<11) + (ck<<7) + coff) = un4; \
    if (nq == ck && c == I)                                                 \
        *(float4*)&dsb[(((size_t)(n0g+I))<<5) + chb] = un4;                 \
    float cx=un4.x, cy=un4.y, cz=un4.z, cw=un4.w;                           \
    float qx=cx*cx, qy=cy*cy, qz=cz*cz, qw=cw*cw;                           \
    cx+=__shfl_xor(cx,8);  cy+=__shfl_xor(cy,8);  cz+=__shfl_xor(cz,8);  cw+=__shfl_xor(cw,8); \
    qx+=__shfl_xor(qx,8);  qy+=__shfl_xor(qy,8);  qz+=__shfl_xor(qz,8);  qw+=__shfl_xor(qw,8); \
    cx+=__shfl_xor(cx,16); cy+=__shfl_xor(cy,16); cz+=__shfl_xor(cz,16); cw+=__shfl_xor(cw,16); \
    qx+=__shfl_xor(qx,16); qy+=__shfl_xor(qy,16); qz+=__shfl_xor(qz,16); qw+=__shfl_xor(qw,16); \
    if (c == 0) {                                                           \
        *(float4*)&pcs[(((size_t)(ck*NLG_ + n0g + I))<<5) + chb] = make_float4(cx,cy,cz,cw); \
        *(float4*)&pss[(((size_t)(ck*NLG_ + n0g + I))<<5) + chb] = make_float4(qx,qy,qz,qw); \
    }                                                                       \
  }

__global__ __launch_bounds__(512, 4) void k_layer(
    const float* __restrict__ u_in, float* __restrict__ u_out,
    const int* __restrict__ offsg, const int* __restrict__ csrp,
    const float* __restrict__ bnaP, const float* __restrict__ bng,
    const float* __restrict__ bnb, int lay, int last,
    const float* __restrict__ rvb, const float* __restrict__ bi,
    const float* __restrict__ u1w,
    const float* __restrict__ liw, const float* __restrict__ lib,
    const float* __restrict__ ljw, const float* __restrict__ ljb,
    const float* __restrict__ dl_l, const float* __restrict__ gtb,
    const float* __restrict__ ef_l,
    float* __restrict__ pcs, float* __restrict__ pss, float* __restrict__ dsb)
{
    __shared__ float us[64*128];
    __shared__ float um[64*128];
    __shared__ int ep[256];
    __shared__ int offs[65];

    const int bid = blockIdx.x, t = threadIdx.x;
    const int g  = ((bid >> 7) << 3) | (bid & 7);
    const int ck = (bid >> 3) & 15;
    const int tw = t & 7, c = (t >> 3) & 3, nq = t >> 5;
    const int chb = tw * 4;
    const int coff = c*32 + chb;
    const int n0g = g*64 + nq*4;

    if (t < 256) ep[t] = csrp[g*256 + t];
    else if (t < 256 + 65) offs[t - 256] = offsg[g*65 + (t - 256)];

    // stage u slice: direct read, or layer-0 synthesis from b_init + rv
    if (lay == 0) {
#pragma unroll
        for (int r = 0; r < 4; ++r) {
            int lin = r*2048 + t*4;
            int nl = lin >> 7, off = lin & 127;
            int ch0 = off & 31, cw = off >> 5;
            float4 v = *(const float4*)(bi + ch0);
            if (ck*4 + cw == nl) {
                float4 rv4 = *(const float4*)(rvb + (size_t)(g*64 + nl)*32 + ch0);
                v.x += rv4.x; v.y += rv4.y; v.z += rv4.z; v.w += rv4.w;
            }
            *(float4*)&us[lin] = v;
        }
    } else {
        const float* ub = u_in + ((size_t)g << 17) + (ck << 7);
#pragma unroll
        for (int r = 0; r < 4; ++r) {
            int lin = r*2048 + t*4;
            int nl = lin >> 7, off = lin & 127;
            float4 v = *(const float4*)(ub + ((size_t)nl << 11) + off);
            *(float4*)&us[lin] = v;
        }
    }

    // dl/gtdl for owned nodes (issued before barrier)
    float4 dl0 = *(const float4*)(dl_l + (((size_t)(n0g+0))<<5) + chb);
    float4 dl1 = *(const float4*)(dl_l + (((size_t)(n0g+1))<<5) + chb);
    float4 dl2 = *(const float4*)(dl_l + (((size_t)(n0g+2))<<5) + chb);
    float4 dl3 = *(const float4*)(dl_l + (((size_t)(n0g+3))<<5) + chb);
    float4 gt0 = *(const float4*)(gtb + (((size_t)(n0g+0))<<5) + chb);
    float4 gt1 = *(const float4*)(gtb + (((size_t)(n0g+1))<<5) + chb);
    float4 gt2 = *(const float4*)(gtb + (((size_t)(n0g+2))<<5) + chb);
    float4 gt3 = *(const float4*)(gtb + (((size_t)(n0g+3))<<5) + chb);

    // BN fold + weights
    float sc4[4], sh4[4];
    if (lay > 0) {
#pragma unroll
        for (int j2 = 0; j2 < 4; ++j2) {
            int bj = chb + j2;
            float m = bnaP[bj] * (1.f/524288.f);
            float v = bnaP[32+bj] * (1.f/524288.f) - m*m;
            float s_ = bng[bj] * rsqrtf(v + 1e-5f);
            sc4[j2] = s_; sh4[j2] = bnb[bj] - m*s_;
        }
    } else {
#pragma unroll
        for (int j2 = 0; j2 < 4; ++j2) { sc4[j2] = 1.f; sh4[j2] = 0.f; }
    }
    float w1f[16], wi[16], wj[16], bli4[4], blj4[4];
#pragma unroll
    for (int j2 = 0; j2 < 4; ++j2)
#pragma unroll
        for (int d = 0; d < 4; ++d) {
            w1f[j2*4+d] = u1w[(chb+j2)*4 + d] * sc4[j2];
            wi [j2*4+d] = liw[(chb+j2)*4 + d];
            wj [j2*4+d] = ljw[(chb+j2)*4 + d];
        }
#pragma unroll
    for (int d = 0; d < 4; ++d) { bli4[d] = lib[chb+d]; blj4[d] = ljb[chb+d]; }

    __syncthreads();

    // um + ui for owned nodes
    float4 ui0, ui1, ui2, ui3;
    UM_NODE(0, ui0, dl0, gt0)
    UM_NODE(1, ui1, dl1, gt1)
    UM_NODE(2, ui2, dl2, gt2)
    UM_NODE(3, ui3, dl3, gt3)
    __syncthreads();

    // edge aggregation from LDS um (2-deep ef prefetch pipeline)
    float4 acc0 = make_float4(0,0,0,0), acc1 = acc0, acc2 = acc0, acc3 = acc0;
    int j = offs[nq*4];
    {
        int ja = j < 255 ? j : 255;
        int pkA = ep[ja];
        float4 efA = *(const float4*)(ef_l + (((size_t)((g<<8)+(pkA>>6)))<<5) + chb);
        int jb = (j+1) < 255 ? (j+1) : 255;
        int pkB = ep[jb];
        float4 efB = *(const float4*)(ef_l + (((size_t)((g<<8)+(pkB>>6)))<<5) + chb);
        int e1 = offs[nq*4+1], e2 = offs[nq*4+2], e3 = offs[nq*4+3], e4 = offs[nq*4+4];
        PROC_NODE(acc0, ui0, e1)
        PROC_NODE(acc1, ui1, e2)
        PROC_NODE(acc2, ui2, e3)
        PROC_NODE(acc3, ui3, e4)
    }

    // update + write + stats
    UN_NODE(0, acc0)
    UN_NODE(1, acc1)
    UN_NODE(2, acc2)
    UN_NODE(3, acc3)
}

// chunk-reduce + bn accumulation + graph extract (+ fused final head)
__global__ __launch_bounds__(256) void k_midx(
    const float* __restrict__ pcs, const float* __restrict__ pss,
    const float* __restrict__ dsb,
    const float* __restrict__ l1w, const float* __restrict__ l1b,
    const float* __restrict__ l2w, const float* __restrict__ l2b,
    const float* __restrict__ lnw, const float* __restrict__ lnb,
    float* __restrict__ csb, float* __restrict__ bna_i,
    float* __restrict__ out_acc, float scale,
    int do_final, const float* __restrict__ acw, const float* __restrict__ acb,
    const float* __restrict__ flw, const float* __restrict__ flb,
    float* __restrict__ outp)
{
    __shared__ float red[3*128];
    __shared__ float S[32], D[32], o1[128], ov[128], t1[128];
    int g = blockIdx.x, t = threadIdx.x;
    int ch = t & 31, ng = t >> 5;
    float pS = 0.f, pQ = 0.f, pD = 0.f;
#pragma unroll
    for (int k = 0; k < 8; ++k) {
        int n = g*64 + ng + 8*k;
        float cs_ = 0.f, ss_ = 0.f;
#pragma unroll
        for (int ckk = 0; ckk < 16; ++ckk) {
            cs_ += pcs[((size_t)ckk*NLG_ + n)*32 + ch];
            ss_ += pss[((size_t)ckk*NLG_ + n)*32 + ch];
        }
        csb[n*32 + ch] = cs_;
        pS += cs_; pQ += ss_;
        pD += dsb[n*32 + ch];
    }
    pS += __shfl_xor(pS, 32); pQ += __shfl_xor(pQ, 32); pD += __shfl_xor(pD, 32);
    int w = t >> 6;
    if ((t & 63) < 32) {
        red[w*32 + ch] = pS;
        red[128 + w*32 + ch] = pQ;
        red[256 + w*32 + ch] = pD;
    }
    __syncthreads();
    if (t < 32) {
        float S_ = 0.f, Q_ = 0.f, D_ = 0.f;
#pragma unroll
        for (int ww = 0; ww < 4; ++ww) {
            S_ += red[ww*32 + t]; Q_ += red[128 + ww*32 + t]; D_ += red[256 + ww*32 + t];
        }
        S[t] = S_; D[t] = D_;
        atomicAdd(&bna_i[t], S_);
        atomicAdd(&bna_i[32 + t], Q_);
    }
    __syncthreads();
    float o = 0.f;
    if (t < 128) {
        o = l1b[t] + l2b[t];
        for (int k = 0; k < 32; ++k)
            o += (S[k]*(1.f/4096.f))*l1w[k*HF_ + t] + (D[k]*(1.f/64.f))*l2w[k*HF_ + t];
        o1[t] = o;
    }
    __syncthreads();
    if (t < 128) {
        float r = lnb[t];
        for (int k = 0; k < 128; ++k) r += o1[k] * lnw[k*HF_ + t];
        float newv = out_acc[g*HF_ + t] + (o + (r > 0.f ? r : 0.f)) * scale;
        out_acc[g*HF_ + t] = newv;
        ov[t] = newv;
    }
    if (do_final) {
        __syncthreads();
        if (t < 128) {
            float r2 = acb[t];
            for (int k = 0; k < 128; ++k) r2 += ov[k] * acw[k*HF_ + t];
            t1[t] = ov[t] + (r2 > 0.f ? r2 : 0.f);
        }
        __syncthreads();
        if (t < NC_) {
            float s2 = flb[t];
            for (int k = 0; k < 128; ++k) s2 += t1[k] * flw[k*NC_ + t];
            outp[g*NC_ + t] = s2;
        }
    }
}

// ---------------------------------------------------------------------------
extern "C" void kernel_launch(void* const* d_in, const int* in_sizes, int n_in,
                              void* d_out, int out_size, void* d_ws, size_t ws_size,
                              hipStream_t stream) {
    const float* x_g      = (const float*)d_in[0];
    const float* eag      = (const float*)d_in[1];
    const float* x_lg     = (const float*)d_in[2];
    const float* ealg     = (const float*)d_in[3];
    const float* W_enc    = (const float*)d_in[4];
    const float* b_enc    = (const float*)d_in[5];
    const float* W_msg    = (const float*)d_in[6];
    const float* b_msg    = (const float*)d_in[7];
    const float* W_init   = (const float*)d_in[8];
    const float* b_init   = (const float*)d_in[9];
    const float* np_l1_w  = (const float*)d_in[10];
    const float* np_l1_b  = (const float*)d_in[11];
    const float* np_l2_w  = (const float*)d_in[12];
    const float* np_l2_b  = (const float*)d_in[13];
    const float* np_lin_w = (const float*)d_in[14];
    const float* np_lin_b = (const float*)d_in[15];
    const float* fe_l1_w  = (const float*)d_in[16];
    const float* fe_l1_b  = (const float*)d_in[17];
    const float* fe_l2_w  = (const float*)d_in[18];
    const float* fe_l2_b  = (const float*)d_in[19];
    const float* fe_lin_w = (const float*)d_in[20];
    const float* fe_lin_b = (const float*)d_in[21];
    const float* gd_w     = (const float*)d_in[22];
    const float* gd_b     = (const float*)d_in[23];
    const float* ga_w     = (const float*)d_in[24];
    const float* ga_b     = (const float*)d_in[25];
    const float* ld_w     = (const float*)d_in[26];
    const float* ld_b     = (const float*)d_in[27];
    const float* la_w     = (const float*)d_in[28];
    const float* la_b     = (const float*)d_in[29];
    const float* u1_w     = (const float*)d_in[30];
    const float* u1_b     = (const float*)d_in[31];
    const float* u2_w     = (const float*)d_in[32];
    const float* u2_b     = (const float*)d_in[33];
    const float* u3_w     = (const float*)d_in[34];
    const float* u3_b     = (const float*)d_in[35];
    const float* en_w     = (const float*)d_in[36];
    const float* en_b     = (const float*)d_in[37];
    const float* li_w     = (const float*)d_in[38];
    const float* li_b     = (const float*)d_in[39];
    const float* lj_w     = (const float*)d_in[40];
    const float* lj_b     = (const float*)d_in[41];
    const float* bn_g     = (const float*)d_in[42];
    const float* bn_b     = (const float*)d_in[43];
    const float* ac_w     = (const float*)d_in[44];
    const float* ac_b     = (const float*)d_in[45];
    const float* fl_w     = (const float*)d_in[46];
    const float* fl_b     = (const float*)d_in[47];
    const int*   ei_g     = (const int*)d_in[48];
    const int*   ei_lg    = (const int*)d_in[49];

    const int* s_g  = ei_g;
    const int* d_g  = ei_g + NLG_;
    const int* ls   = ei_lg;
    const int* ldst = ei_lg + ELG_;

    float* ws = (float*)d_ws;
    size_t o = 0;
    float* ub0  = ws + o; o += (size_t)NLG_ * TILE_;
    float* ub1  = ws + o; o += (size_t)NLG_ * TILE_;
    float* hm   = ws + o; o += (size_t)NLG_ * HF_;
    float* hbuf = ws + o; o += (size_t)NG_ * H_;
    float* dgl  = ws + o; o += (size_t)NLG_ * NB_;
    float* egl  = ws + o; o += (size_t)ELG_ * NB_;
    float* p1b  = ws + o; o += (size_t)NG_ * HF_;
    float* p2b  = ws + o; o += (size_t)NG_ * HF_;
    float* q34b = ws + o; o += (size_t)NLG_ * HF_;
    float* rvb  = ws + o; o += (size_t)NLG_ * 32;
    float* csb  = ws + o; o += (size_t)NLG_ * 32;
    float* dsb  = ws + o; o += (size_t)NLG_ * 32;
    float* gtb  = ws + o; o += (size_t)NLG_ * 32;
    float* pcs  = ws + o; o += (size_t)16 * NLG_ * 32;
    float* pss  = ws + o; o += (size_t)16 * NLG_ * 32;
    float* oac  = ws + o; o += (size_t)G_ * HF_;
    float* bna  = ws + o; o += 256;
    float* dlb  = ws + o; o += (size_t)L_ * NLG_ * 32;
    float* efb  = ws + o; o += (size_t)L_ * ELG_ * 32;
    int*   offsg = (int*)(ws + o); o += G_ * 65;
    int*   csrp  = (int*)(ws + o); o += ELG_;

    kA<<<7425, 256, 0, stream>>>(x_g, W_enc, b_enc, ealg, ga_w, ga_b,
                                 x_lg, gd_w, gd_b, eag, W_msg, b_msg,
                                 ls, ldst,
                                 hbuf, egl, dgl, p1b, p2b, q34b,
                                 offsg, csrp, bna);
    kB<<<21504, 256, 0, stream>>>(p1b, p2b, q34b, s_g, d_g, hm,
                                  dgl, egl, ld_w, ld_b, la_w, la_b,
                                  en_w, en_b, dlb, efb);
    kC<<<1152, 256, 0, stream>>>(hm, W_init, b_init, rvb, csb, dsb,
                                 np_l1_w, np_l1_b, np_l2_w, np_l2_b,
                                 np_lin_w, np_lin_b, oac);

    float* ubufs[2] = {ub0, ub1};
    for (int i = 0; i < L_; ++i) {
        const float* ui = ubufs[i & 1];
        float* uo = ubufs[(i + 1) & 1];
        k_gtdl<<<1024, 256, 0, stream>>>(
            csb, dsb,
            (i > 0 ? bna + (i-1)*64 : bna), bn_g + i*32, bn_b + i*32, i,
            u1_w + i*128, u2_w + i*128, u3_w + i*128,
            u1_b + i*32, u2_b + i*32, u3_b + i*32,
            dlb + (size_t)i*NLG_*32, gtb);
        k_layer<<<2048, 512, 0, stream>>>(
            ui, uo, offsg, csrp,
            (i > 0 ? bna + (i-1)*64 : bna), bn_g + i*32, bn_b + i*32, i,
            (i == L_ - 1) ? 1 : 0,
            rvb, b_init,
            u1_w + i*128,
            li_w + i*128, li_b + i*32,
            lj_w + i*128, lj_b + i*32,
            dlb + (size_t)i*NLG_*32, gtb, efb + (size_t)i*ELG_*32,
            pcs, pss, dsb);
        k_midx<<<G_, 256, 0, stream>>>(
            pcs, pss, dsb,
            fe_l1_w, fe_l1_b, fe_l2_w, fe_l2_b, fe_lin_w, fe_lin_b,
            csb, bna + i*64, oac, 1.0f / (float)L_,
            (i == L_ - 1) ? 1 : 0, ac_w, ac_b, fl_w, fl_b, (float*)d_out);
    }
}